// Round 9
// baseline (373.073 us; speedup 1.0000x reference)
//
#include <hip/hip_runtime.h>
#include <math.h>

#define PI_F 3.14159265358979323846f

// x:[16][64][256][256] f32, weights ×4:[64][64][32][32] f32, out:[16][64][256][256] f32
// modes: ky m=0..63 -> ky = m (m<32) else m+192 ; kx = 0..31
//
// Fully-MFMA pipeline (X2/Cc + frag tables in d_ws):
//   AB: per bi: x-DFT MFMA in two 128-h halves -> 32KB LDS B-frags (packed b64
//       scatter) -> y-DFT MFMA accumulated across halves -> X2
//   C : coalesced-mode channel mix (lanes span modes; W read once, coalesced)
//   DE: Cc -> A-frags (16KB); TRANSPOSED inv-y MFMA -> barrier -> LDS region
//       reused: per row-half, wave-local packed scatter -> inv-x MFMA -> out
//
// Frag conventions (R6-R8 validated):
//   A-frag: row = lane&15, k = (lane>>4)*8 + e
//   B-frag: col = lane&15, k = (lane>>4)*8 + e
//   C/D   : col = lane&15, row = (lane>>4)*4 + reg

static constexpr int T_FA  = 0;         // x-DFT B-frag table  hi|lo (32768 bf16)
static constexpr int T_FE  = 16384;     // inv-x  B-frag table hi|lo (32768 bf16)
static constexpr int T_FBC = 32768;     // y-DFT Cy A-frag     hi|lo (32768 bf16)
static constexpr int T_FBS = 49152;     // y-DFT Sy A-frag     hi|lo (32768 bf16)
static constexpr int T_FD1 = 65536;     // inv-y T1 B-frag     hi|lo (65536 bf16)
static constexpr int T_FD2 = 98304;     // inv-y T2 B-frag     hi|lo (65536 bf16)
static constexpr int T_X2  = 131072;                 // [1024][2048] float2
static constexpr int T_CC  = 131072 + 4194304;       // [1024][2048] float2

typedef __attribute__((ext_vector_type(8))) __bf16 bf16x8;
typedef __attribute__((ext_vector_type(4))) float f32x4;

union B4 { __bf16 b[4]; uint2 u; };

// ---------------- fragment tables ----------------
__global__ __launch_bounds__(256) void k_prep(float* __restrict__ ws) {
  int idx = blockIdx.x * 256 + threadIdx.x;
  const float C = 2.0f * PI_F / 256.0f;
  if (idx < 16384) {
    // FA: B[n=col][k=w]; frag q = kc*4+ns (kc<8)
    int j = idx;
    int e = j & 7, l = (j >> 3) & 63, q = j >> 9;
    int ns = q & 3, kc = q >> 2;
    int w = kc * 32 + ((l >> 4) & 3) * 8 + e;
    int col = ns * 16 + (l & 15);
    int kxi = col & 31;
    float ang = C * (float)((kxi * w) & 255);
    float v = (col < 32) ? cosf(ang) : -sinf(ang);
    __bf16 hv = (__bf16)v;
    __bf16 lv = (__bf16)(v - (float)hv);
    __bf16* fr = (__bf16*)(ws + T_FA);
    fr[j] = hv; fr[16384 + j] = lv;
  } else if (idx < 32768) {
    // FE: B[n=w][k=c]; frag q = kc*16+wblk (kc<2)
    int j = idx - 16384;
    int e = j & 7, l = (j >> 3) & 63, q = j >> 9;
    int wb = q & 15, kc = q >> 4;
    int c = kc * 32 + ((l >> 4) & 3) * 8 + e;
    int w = wb * 16 + (l & 15);
    int kxi = (c < 32) ? c : (c - 32);
    float ang = C * (float)((kxi * w) & 255);
    float v = (c < 32) ? cosf(ang) : sinf(ang);
    __bf16 hv = (__bf16)v;
    __bf16 lv = (__bf16)(v - (float)hv);
    __bf16* fr = (__bf16*)(ws + T_FE);
    fr[j] = hv; fr[16384 + j] = lv;
  } else if (idx < 65536) {
    // FBC/FBS: A[row=m][k=h]; frag q = kc*4+ms4 (kc<8)
    int base = (idx < 49152) ? 32768 : 49152;
    int j = idx - base;
    int e = j & 7, l = (j >> 3) & 63, q = j >> 9;
    int ms4 = q & 3, kc = q >> 2;
    int m = ms4 * 16 + (l & 15);
    int h = kc * 32 + ((l >> 4) & 3) * 8 + e;
    int ky = (m < 32) ? m : (m + 192);
    float ang = C * (float)((ky * h) & 255);
    float v = (idx < 49152) ? cosf(ang) : sinf(ang);
    __bf16 hv = (__bf16)v;
    __bf16 lv = (__bf16)(v - (float)hv);
    __bf16* fr = (__bf16*)(ws + base);
    fr[j] = hv; fr[16384 + j] = lv;
  } else if (idx < 131072) {
    // FD1/FD2: B[k = m-stack 128][col = h]; frag f = (wv*4+kc)*4+nsH
    int base = (idx < 98304) ? T_FD1 : T_FD2;
    int j = idx - base;
    int e = j & 7, l = (j >> 3) & 63, f = j >> 9;     // f 0..63
    int nsH = f & 3, kc = (f >> 2) & 3, wv = f >> 4;
    int h = wv * 64 + nsH * 16 + (l & 15);
    int k = kc * 32 + ((l >> 4) & 3) * 8 + e;
    int m = (k < 64) ? k : (k - 64);
    int ky = (m < 32) ? m : (m + 192);
    float ang = C * (float)((ky * h) & 255);
    float cv = cosf(ang), sv = sinf(ang);
    float v;
    if (idx < 98304) v = (k < 64) ? cv : -sv;    // T1:  cy | -sy  -> Yre
    else             v = (k < 64) ? -sv : -cv;   // T2: -sy | -cy  -> -Yim
    __bf16 hv = (__bf16)v;
    __bf16 lv = (__bf16)(v - (float)hv);
    __bf16* fr = (__bf16*)(ws + base);
    fr[j] = hv; fr[32768 + j] = lv;
  }
}

// split 8 consecutive floats into hi/lo bf16x8 fragments
__device__ __forceinline__ void cvt_split8(const float* __restrict__ p,
                                           bf16x8& h, bf16x8& l) {
  float4 a = *(const float4*)p;
  float4 b = *(const float4*)(p + 4);
#define CVS(e, vv) { __bf16 hh = (__bf16)(vv); h[e] = hh; l[e] = (__bf16)((vv) - (float)hh); }
  CVS(0, a.x) CVS(1, a.y) CVS(2, a.z) CVS(3, a.w)
  CVS(4, b.x) CVS(5, b.y) CVS(6, b.z) CVS(7, b.w)
#undef CVS
}

// ---------------- AB: x-DFT + y-DFT, all MFMA, two h-halves (32KB LDS) ----------------
__global__ __launch_bounds__(256, 3) void k_AB(const float* __restrict__ x,
                                               const float* __restrict__ ws,
                                               float2* __restrict__ X2) {
  __shared__ __bf16 AsH[8192];   // [kc_l 4][ns 4][64 lanes][8 e]  (128 h-rows)
  __shared__ __bf16 AsL[8192];
  const __bf16* frA = (const __bf16*)(ws + T_FA);
  const __bf16* fbc = (const __bf16*)(ws + T_FBC);
  const __bf16* fbs = (const __bf16*)(ws + T_FBS);
  const int t = threadIdx.x, bi = blockIdx.x;
  const int l = t & 63, wv = t >> 6;
  const int lr = l & 15, lk = l >> 4;

  f32x4 cyA[4], syA[4];
#pragma unroll
  for (int n = 0; n < 4; ++n) { cyA[n] = (f32x4){0.f,0.f,0.f,0.f}; syA[n] = (f32x4){0.f,0.f,0.f,0.f}; }

  for (int hh = 0; hh < 2; ++hh) {
    // ---- A phase: wave wv owns rows hh*128 + wv*32 + ms*16 (ms 0..1) ----
    f32x4 acc[2][4];
#pragma unroll
    for (int m = 0; m < 2; ++m)
#pragma unroll
      for (int n = 0; n < 4; ++n) acc[m][n] = (f32x4){0.f, 0.f, 0.f, 0.f};
    const float* xb = x + (size_t)bi * 65536 + (size_t)(hh * 128 + wv * 32 + lr) * 256 + lk * 8;
    for (int kc = 0; kc < 8; ++kc) {
      bf16x8 ah[2], al[2];
#pragma unroll
      for (int ms = 0; ms < 2; ++ms)
        cvt_split8(xb + ms * 16 * 256 + kc * 32, ah[ms], al[ms]);
      bf16x8 bh[4], bl[4];
#pragma unroll
      for (int ns = 0; ns < 4; ++ns) {
        int fo = ((kc * 4 + ns) * 64 + l) * 8;
        bh[ns] = *(const bf16x8*)(frA + fo);
        bl[ns] = *(const bf16x8*)(frA + 16384 + fo);
      }
#pragma unroll
      for (int ms = 0; ms < 2; ++ms)
#pragma unroll
        for (int ns = 0; ns < 4; ++ns) {
          acc[ms][ns] = __builtin_amdgcn_mfma_f32_16x16x32_bf16(ah[ms], bh[ns], acc[ms][ns], 0, 0, 0);
          acc[ms][ns] = __builtin_amdgcn_mfma_f32_16x16x32_bf16(al[ms], bh[ns], acc[ms][ns], 0, 0, 0);
          acc[ms][ns] = __builtin_amdgcn_mfma_f32_16x16x32_bf16(ah[ms], bl[ns], acc[ms][ns], 0, 0, 0);
        }
    }
    __syncthreads();    // prev half's B-phase reads complete before overwrite
    // ---- packed scatter: kc_l = wv, koff = ms*16 + lk*4 + r ----
#pragma unroll
    for (int ms = 0; ms < 2; ++ms)
#pragma unroll
      for (int ns = 0; ns < 4; ++ns) {
        int lp = (ms * 2 + (lk >> 1)) * 16 + lr;
        int base = ((wv * 4 + ns) * 64 + lp) * 8 + (lk & 1) * 4;
        B4 ph, pl;
#pragma unroll
        for (int r = 0; r < 4; ++r) {
          float v = acc[ms][ns][r];
          __bf16 hv = (__bf16)v;
          ph.b[r] = hv; pl.b[r] = (__bf16)(v - (float)hv);
        }
        *(uint2*)&AsH[base] = ph.u;
        *(uint2*)&AsL[base] = pl.u;
      }
    __syncthreads();
    // ---- B phase: kc_l 0..3 (global h-chunk hh*4 + kc_l) ----
    for (int kc_l = 0; kc_l < 4; ++kc_l) {
      bf16x8 Bh[4], Bl[4];
#pragma unroll
      for (int ns = 0; ns < 4; ++ns) {
        int fo = ((kc_l * 4 + ns) * 64 + l) * 8;
        Bh[ns] = *(const bf16x8*)(AsH + fo);
        Bl[ns] = *(const bf16x8*)(AsL + fo);
      }
      int ao = (((hh * 4 + kc_l) * 4 + wv) * 64 + l) * 8;
      bf16x8 cyh = *(const bf16x8*)(fbc + ao);
      bf16x8 cyl = *(const bf16x8*)(fbc + 16384 + ao);
      bf16x8 syh = *(const bf16x8*)(fbs + ao);
      bf16x8 syl = *(const bf16x8*)(fbs + 16384 + ao);
#pragma unroll
      for (int ns = 0; ns < 4; ++ns) {
        cyA[ns] = __builtin_amdgcn_mfma_f32_16x16x32_bf16(cyh, Bh[ns], cyA[ns], 0, 0, 0);
        cyA[ns] = __builtin_amdgcn_mfma_f32_16x16x32_bf16(cyl, Bh[ns], cyA[ns], 0, 0, 0);
        cyA[ns] = __builtin_amdgcn_mfma_f32_16x16x32_bf16(cyh, Bl[ns], cyA[ns], 0, 0, 0);
        syA[ns] = __builtin_amdgcn_mfma_f32_16x16x32_bf16(syh, Bh[ns], syA[ns], 0, 0, 0);
        syA[ns] = __builtin_amdgcn_mfma_f32_16x16x32_bf16(syl, Bh[ns], syA[ns], 0, 0, 0);
        syA[ns] = __builtin_amdgcn_mfma_f32_16x16x32_bf16(syh, Bl[ns], syA[ns], 0, 0, 0);
      }
    }
  }
  // ---- combine halves and store X2 ----
#pragma unroll
  for (int ns = 0; ns < 2; ++ns)
#pragma unroll
    for (int r = 0; r < 4; ++r) {
      int m = wv * 16 + lk * 4 + r;
      int kx = ns * 16 + lr;
      float re = cyA[ns][r] + syA[ns + 2][r];
      float im = cyA[ns + 2][r] - syA[ns][r];
      X2[(size_t)bi * 2048 + m * 32 + kx] = make_float2(re, im);
    }
}

// ---------------- C: channel mix, coalesced-mode ----------------
// grid 1024: mc = bid&63 (32-mode chunk), ot = bid>>6 (4-o tile).
__global__ __launch_bounds__(256, 4) void k_C(const float2* __restrict__ X2,
                                              const float* __restrict__ wpr,
                                              const float* __restrict__ wpi,
                                              const float* __restrict__ wnr,
                                              const float* __restrict__ wni,
                                              float2* __restrict__ Cc) {
  __shared__ float2 Xs[2][16][32];     // [buf][b][md]
  __shared__ float2 Ws[2][4][4][32];   // [buf][iS][og][md]
  const int t = threadIdx.x;
  const int mc = blockIdx.x & 63, ot = blockIdx.x >> 6;
  const int mode0 = mc * 32;
  const float *wr, *wi; int wm0;
  if (mode0 < 1024) { wr = wpr; wi = wpi; wm0 = mode0; }
  else              { wr = wnr; wi = wni; wm0 = mode0 - 1024; }
  const int md = t & 31, og2 = (t >> 5) & 1, bq = t >> 6;
  const int bS = t >> 4, c2 = (t & 15) * 2;
  const int e0 = t * 2;
  const int wiS = e0 >> 7, wog = (e0 >> 5) & 3, wmd = e0 & 31;

  float ar[4][2], ai[4][2];
#pragma unroll
  for (int b = 0; b < 4; ++b) { ar[b][0]=0.f; ar[b][1]=0.f; ai[b][0]=0.f; ai[b][1]=0.f; }

  *(float4*)&Xs[0][bS][c2] =
      *(const float4*)&X2[((size_t)(bS * 64 + 0)) * 2048 + mode0 + c2];
  {
    size_t wa = ((size_t)(wiS * 64) + ot * 4 + wog) * 1024 + wm0 + wmd;
    float2 r2 = *(const float2*)&wr[wa];
    float2 i2 = *(const float2*)&wi[wa];
    Ws[0][wiS][wog][wmd]     = make_float2(r2.x, i2.x);
    Ws[0][wiS][wog][wmd + 1] = make_float2(r2.y, i2.y);
  }
  __syncthreads();

  for (int i = 0; i < 64; ++i) {
    const int cur = i & 1, wcur = (i >> 2) & 1;
    if (i < 63)
      *(float4*)&Xs[cur ^ 1][bS][c2] =
          *(const float4*)&X2[((size_t)(bS * 64 + i + 1)) * 2048 + mode0 + c2];
    if ((i & 3) == 0 && i < 60) {
      size_t wa = ((size_t)((i + 4 + wiS) * 64) + ot * 4 + wog) * 1024 + wm0 + wmd;
      float2 r2 = *(const float2*)&wr[wa];
      float2 i2 = *(const float2*)&wi[wa];
      Ws[wcur ^ 1][wiS][wog][wmd]     = make_float2(r2.x, i2.x);
      Ws[wcur ^ 1][wiS][wog][wmd + 1] = make_float2(r2.y, i2.y);
    }
    float2 w0 = Ws[wcur][i & 3][og2 * 2 + 0][md];
    float2 w1 = Ws[wcur][i & 3][og2 * 2 + 1][md];
#pragma unroll
    for (int b = 0; b < 4; ++b) {
      float2 xv = Xs[cur][bq * 4 + b][md];
      ar[b][0] = fmaf(xv.x, w0.x, fmaf(-xv.y, w0.y, ar[b][0]));
      ai[b][0] = fmaf(xv.x, w0.y, fmaf( xv.y, w0.x, ai[b][0]));
      ar[b][1] = fmaf(xv.x, w1.x, fmaf(-xv.y, w1.y, ar[b][1]));
      ai[b][1] = fmaf(xv.x, w1.y, fmaf( xv.y, w1.x, ai[b][1]));
    }
    __syncthreads();
  }

  const float scale = ((md == 0) ? 1.f : 2.f) * (1.f / 65536.f);
#pragma unroll
  for (int b = 0; b < 4; ++b)
#pragma unroll
    for (int o2 = 0; o2 < 2; ++o2)
      Cc[((size_t)((bq * 4 + b) * 64 + ot * 4 + og2 * 2 + o2)) * 2048 + mode0 + md] =
          make_float2(ar[b][o2] * scale, ai[b][o2] * scale);
}

// ---------------- DE: transposed inv-y + inv-x + Re(), 32KB aliased LDS ----------------
__global__ __launch_bounds__(256, 3) void k_DE(const float2* __restrict__ Cc,
                                               const float* __restrict__ ws,
                                               float* __restrict__ out) {
  __shared__ __bf16 smem[16384];            // 32KB, time-shared
  __bf16* CH = smem;                        // phase 1: Cstack^T A-frags hi (8KB)
  __bf16* CL = smem + 4096;                 //          lo (8KB)
  __bf16* EH = smem;                        // phase 2: Y E-A-frags (row-half) hi (16KB)
  __bf16* EL = smem + 8192;                 //          lo (16KB)
  const __bf16* fd1 = (const __bf16*)(ws + T_FD1);
  const __bf16* fd2 = (const __bf16*)(ws + T_FD2);
  const __bf16* frE = (const __bf16*)(ws + T_FE);
  const int t = threadIdx.x, bo = blockIdx.x;
  const int l = t & 63, wv = t >> 6;
  const int lr = l & 15, lk = l >> 4;

  // ---- stage Cc -> A-frag LDS: row = kx, k = m (Cr) | m+64 (Ci) ----
  const float2* Cp = Cc + (size_t)bo * 2048;
#pragma unroll
  for (int jj = 0; jj < 8; ++jj) {
    int j = t + 256 * jj;
    float2 v = Cp[j];
    int m = j >> 5, kx = j & 31;
    int msK = kx >> 4, lA = ((m >> 3) & 3) * 16 + (kx & 15);
    int e = m & 7, kcR = m >> 5;
    int idxR = ((msK * 4 + kcR) * 64 + lA) * 8 + e;
    int idxI = ((msK * 4 + kcR + 2) * 64 + lA) * 8 + e;
    __bf16 h1 = (__bf16)v.x; CH[idxR] = h1; CL[idxR] = (__bf16)(v.x - (float)h1);
    __bf16 h2 = (__bf16)v.y; CH[idxI] = h2; CL[idxI] = (__bf16)(v.y - (float)h2);
  }
  __syncthreads();

  // ---- D phase (transposed): z1 = Yre^T, z2 = (-Yim)^T ----
  f32x4 z1[2][4], z2[2][4];
#pragma unroll
  for (int m = 0; m < 2; ++m)
#pragma unroll
    for (int n = 0; n < 4; ++n) { z1[m][n] = (f32x4){0.f,0.f,0.f,0.f}; z2[m][n] = (f32x4){0.f,0.f,0.f,0.f}; }
  for (int kc = 0; kc < 4; ++kc) {
    bf16x8 ah[2], al[2];
#pragma unroll
    for (int msK = 0; msK < 2; ++msK) {
      int fo = ((msK * 4 + kc) * 64 + l) * 8;
      ah[msK] = *(const bf16x8*)(CH + fo);
      al[msK] = *(const bf16x8*)(CL + fo);
    }
#pragma unroll
    for (int nsH = 0; nsH < 4; ++nsH) {
      int bo_ = (((wv * 4 + kc) * 4 + nsH) * 64 + l) * 8;
      bf16x8 b1h = *(const bf16x8*)(fd1 + bo_);
      bf16x8 b1l = *(const bf16x8*)(fd1 + 32768 + bo_);
      bf16x8 b2h = *(const bf16x8*)(fd2 + bo_);
      bf16x8 b2l = *(const bf16x8*)(fd2 + 32768 + bo_);
#pragma unroll
      for (int msK = 0; msK < 2; ++msK) {
        z1[msK][nsH] = __builtin_amdgcn_mfma_f32_16x16x32_bf16(ah[msK], b1h, z1[msK][nsH], 0, 0, 0);
        z1[msK][nsH] = __builtin_amdgcn_mfma_f32_16x16x32_bf16(al[msK], b1h, z1[msK][nsH], 0, 0, 0);
        z1[msK][nsH] = __builtin_amdgcn_mfma_f32_16x16x32_bf16(ah[msK], b1l, z1[msK][nsH], 0, 0, 0);
        z2[msK][nsH] = __builtin_amdgcn_mfma_f32_16x16x32_bf16(ah[msK], b2h, z2[msK][nsH], 0, 0, 0);
        z2[msK][nsH] = __builtin_amdgcn_mfma_f32_16x16x32_bf16(al[msK], b2h, z2[msK][nsH], 0, 0, 0);
        z2[msK][nsH] = __builtin_amdgcn_mfma_f32_16x16x32_bf16(ah[msK], b2l, z2[msK][nsH], 0, 0, 0);
      }
    }
  }
  __syncthreads();   // all D-phase CH/CL reads done before region reuse

  // ---- per row-half: wave-local scatter -> E A-frags -> inv-x MFMA -> out ----
  float* ob = out + (size_t)bo * 65536;
  for (int p = 0; p < 2; ++p) {
    // scatter nsH in {2p, 2p+1}: value (msK,nsH,r): kx = msK*16+lk*4+r,
    // h_local = nsH*16+lr; E idx: (((wv*2+q)*2+kcE)*64 + lp)*8 + e
#pragma unroll
    for (int msK = 0; msK < 2; ++msK)
#pragma unroll
      for (int q = 0; q < 2; ++q) {
        int nsH = 2 * p + q;
        int lp = (msK * 2 + (lk >> 1)) * 16 + lr;
        int eb = (lk & 1) * 4;
        int base1 = (((wv * 2 + q) * 2 + 0) * 64 + lp) * 8 + eb;
        int base2 = (((wv * 2 + q) * 2 + 1) * 64 + lp) * 8 + eb;
        B4 p1h, p1l, p2h, p2l;
#pragma unroll
        for (int r = 0; r < 4; ++r) {
          float v1 = z1[msK][nsH][r];
          __bf16 h1 = (__bf16)v1; p1h.b[r] = h1; p1l.b[r] = (__bf16)(v1 - (float)h1);
          float v2 = z2[msK][nsH][r];
          __bf16 h2 = (__bf16)v2; p2h.b[r] = h2; p2l.b[r] = (__bf16)(v2 - (float)h2);
        }
        *(uint2*)&EH[base1] = p1h.u; *(uint2*)&EL[base1] = p1l.u;
        *(uint2*)&EH[base2] = p2h.u; *(uint2*)&EL[base2] = p2l.u;
      }
    // wave-local handoff: no __syncthreads needed (same-wave LDS ordering)
    bf16x8 ah[2][2], al[2][2];
#pragma unroll
    for (int q = 0; q < 2; ++q)
#pragma unroll
      for (int kc = 0; kc < 2; ++kc) {
        int fo = (((wv * 2 + q) * 2 + kc) * 64 + l) * 8;
        ah[q][kc] = *(const bf16x8*)(EH + fo);
        al[q][kc] = *(const bf16x8*)(EL + fo);
      }
    for (int cb = 0; cb < 4; ++cb) {
      f32x4 eacc[2][4];
#pragma unroll
      for (int m = 0; m < 2; ++m)
#pragma unroll
        for (int n = 0; n < 4; ++n) eacc[m][n] = (f32x4){0.f, 0.f, 0.f, 0.f};
#pragma unroll
      for (int kc = 0; kc < 2; ++kc) {
        bf16x8 bh[4], bl[4];
#pragma unroll
        for (int ns = 0; ns < 4; ++ns) {
          int fo = ((kc * 16 + cb * 4 + ns) * 64 + l) * 8;
          bh[ns] = *(const bf16x8*)(frE + fo);
          bl[ns] = *(const bf16x8*)(frE + 16384 + fo);
        }
#pragma unroll
        for (int q = 0; q < 2; ++q)
#pragma unroll
          for (int ns = 0; ns < 4; ++ns) {
            eacc[q][ns] = __builtin_amdgcn_mfma_f32_16x16x32_bf16(ah[q][kc], bh[ns], eacc[q][ns], 0, 0, 0);
            eacc[q][ns] = __builtin_amdgcn_mfma_f32_16x16x32_bf16(al[q][kc], bh[ns], eacc[q][ns], 0, 0, 0);
            eacc[q][ns] = __builtin_amdgcn_mfma_f32_16x16x32_bf16(ah[q][kc], bl[ns], eacc[q][ns], 0, 0, 0);
          }
      }
#pragma unroll
      for (int q = 0; q < 2; ++q)
#pragma unroll
        for (int ns = 0; ns < 4; ++ns) {
          int col = cb * 64 + ns * 16 + lr;
          int row0 = wv * 64 + (2 * p + q) * 16 + lk * 4;
#pragma unroll
          for (int r = 0; r < 4; ++r)
            ob[(size_t)(row0 + r) * 256 + col] = eacc[q][ns][r];
        }
    }
  }
}

extern "C" void kernel_launch(void* const* d_in, const int* in_sizes, int n_in,
                              void* d_out, int out_size, void* d_ws, size_t ws_size,
                              hipStream_t stream) {
  (void)in_sizes; (void)n_in; (void)out_size; (void)ws_size;
  const float* x   = (const float*)d_in[0];
  const float* wpr = (const float*)d_in[1];
  const float* wpi = (const float*)d_in[2];
  const float* wnr = (const float*)d_in[3];
  const float* wni = (const float*)d_in[4];
  float* out = (float*)d_out;
  float* ws  = (float*)d_ws;

  float2* X2 = (float2*)(ws + T_X2);   // [1024][2048] float2
  float2* Cc = (float2*)(ws + T_CC);   // [1024][2048] float2

  k_prep<<<512, 256, 0, stream>>>(ws);
  k_AB<<<1024, 256, 0, stream>>>(x, ws, X2);
  k_C<<<1024, 256, 0, stream>>>(X2, wpr, wpi, wnr, wni, Cc);
  k_DE<<<1024, 256, 0, stream>>>(Cc, ws, out);
}

// Round 10
// 268.322 us; speedup vs baseline: 1.3904x; 1.3904x over previous
//
#include <hip/hip_runtime.h>
#include <math.h>

#define PI_F 3.14159265358979323846f

// x:[16][64][256][256] f32, weights ×4:[64][64][32][32] f32, out:[16][64][256][256] f32
// modes: ky m=0..63 -> ky = m (m<32) else m+192 ; kx = 0..31
//
// Fully-MFMA pipeline (X2/Cc + frag tables in d_ws):
//   AB: per bi: x-DFT MFMA in two 128-h halves -> 32KB LDS B-frags (packed b64
//       scatter) -> y-DFT MFMA accumulated across halves -> X2
//   C : coalesced-mode channel mix (lanes span modes; W read once, coalesced)
//   DE: Cc -> A-frags (16KB); TRANSPOSED inv-y MFMA -> barrier -> LDS region
//       reused: per row-half, wave-local packed scatter -> inv-x MFMA -> out
//
// LESSON (R9): __launch_bounds__(256,3) capped unified VGPR+AGPR at ~168 and
// spilled the MFMA accumulators -> 225 MB scratch writes, 4x slowdown. Keep
// (256,2); occupancy 3 comes naturally from the reduced register/LDS footprint.
//
// Frag conventions (R6-R8 validated):
//   A-frag: row = lane&15, k = (lane>>4)*8 + e
//   B-frag: col = lane&15, k = (lane>>4)*8 + e
//   C/D   : col = lane&15, row = (lane>>4)*4 + reg

static constexpr int T_FA  = 0;         // x-DFT B-frag table  hi|lo (32768 bf16)
static constexpr int T_FE  = 16384;     // inv-x  B-frag table hi|lo (32768 bf16)
static constexpr int T_FBC = 32768;     // y-DFT Cy A-frag     hi|lo (32768 bf16)
static constexpr int T_FBS = 49152;     // y-DFT Sy A-frag     hi|lo (32768 bf16)
static constexpr int T_FD1 = 65536;     // inv-y T1 B-frag     hi|lo (65536 bf16)
static constexpr int T_FD2 = 98304;     // inv-y T2 B-frag     hi|lo (65536 bf16)
static constexpr int T_X2  = 131072;                 // [1024][2048] float2
static constexpr int T_CC  = 131072 + 4194304;       // [1024][2048] float2

typedef __attribute__((ext_vector_type(8))) __bf16 bf16x8;
typedef __attribute__((ext_vector_type(4))) float f32x4;

union B4 { __bf16 b[4]; uint2 u; };

// ---------------- fragment tables ----------------
__global__ __launch_bounds__(256) void k_prep(float* __restrict__ ws) {
  int idx = blockIdx.x * 256 + threadIdx.x;
  const float C = 2.0f * PI_F / 256.0f;
  if (idx < 16384) {
    // FA: B[n=col][k=w]; frag q = kc*4+ns (kc<8)
    int j = idx;
    int e = j & 7, l = (j >> 3) & 63, q = j >> 9;
    int ns = q & 3, kc = q >> 2;
    int w = kc * 32 + ((l >> 4) & 3) * 8 + e;
    int col = ns * 16 + (l & 15);
    int kxi = col & 31;
    float ang = C * (float)((kxi * w) & 255);
    float v = (col < 32) ? cosf(ang) : -sinf(ang);
    __bf16 hv = (__bf16)v;
    __bf16 lv = (__bf16)(v - (float)hv);
    __bf16* fr = (__bf16*)(ws + T_FA);
    fr[j] = hv; fr[16384 + j] = lv;
  } else if (idx < 32768) {
    // FE: B[n=w][k=c]; frag q = kc*16+wblk (kc<2)
    int j = idx - 16384;
    int e = j & 7, l = (j >> 3) & 63, q = j >> 9;
    int wb = q & 15, kc = q >> 4;
    int c = kc * 32 + ((l >> 4) & 3) * 8 + e;
    int w = wb * 16 + (l & 15);
    int kxi = (c < 32) ? c : (c - 32);
    float ang = C * (float)((kxi * w) & 255);
    float v = (c < 32) ? cosf(ang) : sinf(ang);
    __bf16 hv = (__bf16)v;
    __bf16 lv = (__bf16)(v - (float)hv);
    __bf16* fr = (__bf16*)(ws + T_FE);
    fr[j] = hv; fr[16384 + j] = lv;
  } else if (idx < 65536) {
    // FBC/FBS: A[row=m][k=h]; frag q = kc*4+ms4 (kc<8)
    int base = (idx < 49152) ? 32768 : 49152;
    int j = idx - base;
    int e = j & 7, l = (j >> 3) & 63, q = j >> 9;
    int ms4 = q & 3, kc = q >> 2;
    int m = ms4 * 16 + (l & 15);
    int h = kc * 32 + ((l >> 4) & 3) * 8 + e;
    int ky = (m < 32) ? m : (m + 192);
    float ang = C * (float)((ky * h) & 255);
    float v = (idx < 49152) ? cosf(ang) : sinf(ang);
    __bf16 hv = (__bf16)v;
    __bf16 lv = (__bf16)(v - (float)hv);
    __bf16* fr = (__bf16*)(ws + base);
    fr[j] = hv; fr[16384 + j] = lv;
  } else if (idx < 131072) {
    // FD1/FD2: B[k = m-stack 128][col = h]; frag f = (wv*4+kc)*4+nsH
    int base = (idx < 98304) ? T_FD1 : T_FD2;
    int j = idx - base;
    int e = j & 7, l = (j >> 3) & 63, f = j >> 9;     // f 0..63
    int nsH = f & 3, kc = (f >> 2) & 3, wv = f >> 4;
    int h = wv * 64 + nsH * 16 + (l & 15);
    int k = kc * 32 + ((l >> 4) & 3) * 8 + e;
    int m = (k < 64) ? k : (k - 64);
    int ky = (m < 32) ? m : (m + 192);
    float ang = C * (float)((ky * h) & 255);
    float cv = cosf(ang), sv = sinf(ang);
    float v;
    if (idx < 98304) v = (k < 64) ? cv : -sv;    // T1:  cy | -sy  -> Yre
    else             v = (k < 64) ? -sv : -cv;   // T2: -sy | -cy  -> -Yim
    __bf16 hv = (__bf16)v;
    __bf16 lv = (__bf16)(v - (float)hv);
    __bf16* fr = (__bf16*)(ws + base);
    fr[j] = hv; fr[32768 + j] = lv;
  }
}

// split 8 consecutive floats into hi/lo bf16x8 fragments
__device__ __forceinline__ void cvt_split8(const float* __restrict__ p,
                                           bf16x8& h, bf16x8& l) {
  float4 a = *(const float4*)p;
  float4 b = *(const float4*)(p + 4);
#define CVS(e, vv) { __bf16 hh = (__bf16)(vv); h[e] = hh; l[e] = (__bf16)((vv) - (float)hh); }
  CVS(0, a.x) CVS(1, a.y) CVS(2, a.z) CVS(3, a.w)
  CVS(4, b.x) CVS(5, b.y) CVS(6, b.z) CVS(7, b.w)
#undef CVS
}

// ---------------- AB: x-DFT + y-DFT, all MFMA, two h-halves (32KB LDS) ----------------
__global__ __launch_bounds__(256, 2) void k_AB(const float* __restrict__ x,
                                               const float* __restrict__ ws,
                                               float2* __restrict__ X2) {
  __shared__ __bf16 AsH[8192];   // [kc_l 4][ns 4][64 lanes][8 e]  (128 h-rows)
  __shared__ __bf16 AsL[8192];
  const __bf16* frA = (const __bf16*)(ws + T_FA);
  const __bf16* fbc = (const __bf16*)(ws + T_FBC);
  const __bf16* fbs = (const __bf16*)(ws + T_FBS);
  const int t = threadIdx.x, bi = blockIdx.x;
  const int l = t & 63, wv = t >> 6;
  const int lr = l & 15, lk = l >> 4;

  f32x4 cyA[4], syA[4];
#pragma unroll
  for (int n = 0; n < 4; ++n) { cyA[n] = (f32x4){0.f,0.f,0.f,0.f}; syA[n] = (f32x4){0.f,0.f,0.f,0.f}; }

  for (int hh = 0; hh < 2; ++hh) {
    // ---- A phase: wave wv owns rows hh*128 + wv*32 + ms*16 (ms 0..1) ----
    f32x4 acc[2][4];
#pragma unroll
    for (int m = 0; m < 2; ++m)
#pragma unroll
      for (int n = 0; n < 4; ++n) acc[m][n] = (f32x4){0.f, 0.f, 0.f, 0.f};
    const float* xb = x + (size_t)bi * 65536 + (size_t)(hh * 128 + wv * 32 + lr) * 256 + lk * 8;
    for (int kc = 0; kc < 8; ++kc) {
      bf16x8 ah[2], al[2];
#pragma unroll
      for (int ms = 0; ms < 2; ++ms)
        cvt_split8(xb + ms * 16 * 256 + kc * 32, ah[ms], al[ms]);
      bf16x8 bh[4], bl[4];
#pragma unroll
      for (int ns = 0; ns < 4; ++ns) {
        int fo = ((kc * 4 + ns) * 64 + l) * 8;
        bh[ns] = *(const bf16x8*)(frA + fo);
        bl[ns] = *(const bf16x8*)(frA + 16384 + fo);
      }
#pragma unroll
      for (int ms = 0; ms < 2; ++ms)
#pragma unroll
        for (int ns = 0; ns < 4; ++ns) {
          acc[ms][ns] = __builtin_amdgcn_mfma_f32_16x16x32_bf16(ah[ms], bh[ns], acc[ms][ns], 0, 0, 0);
          acc[ms][ns] = __builtin_amdgcn_mfma_f32_16x16x32_bf16(al[ms], bh[ns], acc[ms][ns], 0, 0, 0);
          acc[ms][ns] = __builtin_amdgcn_mfma_f32_16x16x32_bf16(ah[ms], bl[ns], acc[ms][ns], 0, 0, 0);
        }
    }
    __syncthreads();    // prev half's B-phase reads complete before overwrite
    // ---- packed scatter: kc_l = wv, koff = ms*16 + lk*4 + r ----
#pragma unroll
    for (int ms = 0; ms < 2; ++ms)
#pragma unroll
      for (int ns = 0; ns < 4; ++ns) {
        int lp = (ms * 2 + (lk >> 1)) * 16 + lr;
        int base = ((wv * 4 + ns) * 64 + lp) * 8 + (lk & 1) * 4;
        B4 ph, pl;
#pragma unroll
        for (int r = 0; r < 4; ++r) {
          float v = acc[ms][ns][r];
          __bf16 hv = (__bf16)v;
          ph.b[r] = hv; pl.b[r] = (__bf16)(v - (float)hv);
        }
        *(uint2*)&AsH[base] = ph.u;
        *(uint2*)&AsL[base] = pl.u;
      }
    __syncthreads();
    // ---- B phase: kc_l 0..3 (global h-chunk hh*4 + kc_l) ----
    for (int kc_l = 0; kc_l < 4; ++kc_l) {
      bf16x8 Bh[4], Bl[4];
#pragma unroll
      for (int ns = 0; ns < 4; ++ns) {
        int fo = ((kc_l * 4 + ns) * 64 + l) * 8;
        Bh[ns] = *(const bf16x8*)(AsH + fo);
        Bl[ns] = *(const bf16x8*)(AsL + fo);
      }
      int ao = (((hh * 4 + kc_l) * 4 + wv) * 64 + l) * 8;
      bf16x8 cyh = *(const bf16x8*)(fbc + ao);
      bf16x8 cyl = *(const bf16x8*)(fbc + 16384 + ao);
      bf16x8 syh = *(const bf16x8*)(fbs + ao);
      bf16x8 syl = *(const bf16x8*)(fbs + 16384 + ao);
#pragma unroll
      for (int ns = 0; ns < 4; ++ns) {
        cyA[ns] = __builtin_amdgcn_mfma_f32_16x16x32_bf16(cyh, Bh[ns], cyA[ns], 0, 0, 0);
        cyA[ns] = __builtin_amdgcn_mfma_f32_16x16x32_bf16(cyl, Bh[ns], cyA[ns], 0, 0, 0);
        cyA[ns] = __builtin_amdgcn_mfma_f32_16x16x32_bf16(cyh, Bl[ns], cyA[ns], 0, 0, 0);
        syA[ns] = __builtin_amdgcn_mfma_f32_16x16x32_bf16(syh, Bh[ns], syA[ns], 0, 0, 0);
        syA[ns] = __builtin_amdgcn_mfma_f32_16x16x32_bf16(syl, Bh[ns], syA[ns], 0, 0, 0);
        syA[ns] = __builtin_amdgcn_mfma_f32_16x16x32_bf16(syh, Bl[ns], syA[ns], 0, 0, 0);
      }
    }
  }
  // ---- combine halves and store X2 ----
#pragma unroll
  for (int ns = 0; ns < 2; ++ns)
#pragma unroll
    for (int r = 0; r < 4; ++r) {
      int m = wv * 16 + lk * 4 + r;
      int kx = ns * 16 + lr;
      float re = cyA[ns][r] + syA[ns + 2][r];
      float im = cyA[ns + 2][r] - syA[ns][r];
      X2[(size_t)bi * 2048 + m * 32 + kx] = make_float2(re, im);
    }
}

// ---------------- C: channel mix, coalesced-mode ----------------
// grid 1024: mc = bid&63 (32-mode chunk), ot = bid>>6 (4-o tile).
__global__ __launch_bounds__(256, 4) void k_C(const float2* __restrict__ X2,
                                              const float* __restrict__ wpr,
                                              const float* __restrict__ wpi,
                                              const float* __restrict__ wnr,
                                              const float* __restrict__ wni,
                                              float2* __restrict__ Cc) {
  __shared__ float2 Xs[2][16][32];     // [buf][b][md]
  __shared__ float2 Ws[2][4][4][32];   // [buf][iS][og][md]
  const int t = threadIdx.x;
  const int mc = blockIdx.x & 63, ot = blockIdx.x >> 6;
  const int mode0 = mc * 32;
  const float *wr, *wi; int wm0;
  if (mode0 < 1024) { wr = wpr; wi = wpi; wm0 = mode0; }
  else              { wr = wnr; wi = wni; wm0 = mode0 - 1024; }
  const int md = t & 31, og2 = (t >> 5) & 1, bq = t >> 6;
  const int bS = t >> 4, c2 = (t & 15) * 2;
  const int e0 = t * 2;
  const int wiS = e0 >> 7, wog = (e0 >> 5) & 3, wmd = e0 & 31;

  float ar[4][2], ai[4][2];
#pragma unroll
  for (int b = 0; b < 4; ++b) { ar[b][0]=0.f; ar[b][1]=0.f; ai[b][0]=0.f; ai[b][1]=0.f; }

  *(float4*)&Xs[0][bS][c2] =
      *(const float4*)&X2[((size_t)(bS * 64 + 0)) * 2048 + mode0 + c2];
  {
    size_t wa = ((size_t)(wiS * 64) + ot * 4 + wog) * 1024 + wm0 + wmd;
    float2 r2 = *(const float2*)&wr[wa];
    float2 i2 = *(const float2*)&wi[wa];
    Ws[0][wiS][wog][wmd]     = make_float2(r2.x, i2.x);
    Ws[0][wiS][wog][wmd + 1] = make_float2(r2.y, i2.y);
  }
  __syncthreads();

  for (int i = 0; i < 64; ++i) {
    const int cur = i & 1, wcur = (i >> 2) & 1;
    if (i < 63)
      *(float4*)&Xs[cur ^ 1][bS][c2] =
          *(const float4*)&X2[((size_t)(bS * 64 + i + 1)) * 2048 + mode0 + c2];
    if ((i & 3) == 0 && i < 60) {
      size_t wa = ((size_t)((i + 4 + wiS) * 64) + ot * 4 + wog) * 1024 + wm0 + wmd;
      float2 r2 = *(const float2*)&wr[wa];
      float2 i2 = *(const float2*)&wi[wa];
      Ws[wcur ^ 1][wiS][wog][wmd]     = make_float2(r2.x, i2.x);
      Ws[wcur ^ 1][wiS][wog][wmd + 1] = make_float2(r2.y, i2.y);
    }
    float2 w0 = Ws[wcur][i & 3][og2 * 2 + 0][md];
    float2 w1 = Ws[wcur][i & 3][og2 * 2 + 1][md];
#pragma unroll
    for (int b = 0; b < 4; ++b) {
      float2 xv = Xs[cur][bq * 4 + b][md];
      ar[b][0] = fmaf(xv.x, w0.x, fmaf(-xv.y, w0.y, ar[b][0]));
      ai[b][0] = fmaf(xv.x, w0.y, fmaf( xv.y, w0.x, ai[b][0]));
      ar[b][1] = fmaf(xv.x, w1.x, fmaf(-xv.y, w1.y, ar[b][1]));
      ai[b][1] = fmaf(xv.x, w1.y, fmaf( xv.y, w1.x, ai[b][1]));
    }
    __syncthreads();
  }

  const float scale = ((md == 0) ? 1.f : 2.f) * (1.f / 65536.f);
#pragma unroll
  for (int b = 0; b < 4; ++b)
#pragma unroll
    for (int o2 = 0; o2 < 2; ++o2)
      Cc[((size_t)((bq * 4 + b) * 64 + ot * 4 + og2 * 2 + o2)) * 2048 + mode0 + md] =
          make_float2(ar[b][o2] * scale, ai[b][o2] * scale);
}

// ---------------- DE: transposed inv-y + inv-x + Re(), 32KB aliased LDS ----------------
__global__ __launch_bounds__(256, 2) void k_DE(const float2* __restrict__ Cc,
                                               const float* __restrict__ ws,
                                               float* __restrict__ out) {
  __shared__ __bf16 smem[16384];            // 32KB, time-shared
  __bf16* CH = smem;                        // phase 1: Cstack^T A-frags hi (8KB)
  __bf16* CL = smem + 4096;                 //          lo (8KB)
  __bf16* EH = smem;                        // phase 2: Y E-A-frags (row-half) hi (16KB)
  __bf16* EL = smem + 8192;                 //          lo (16KB)
  const __bf16* fd1 = (const __bf16*)(ws + T_FD1);
  const __bf16* fd2 = (const __bf16*)(ws + T_FD2);
  const __bf16* frE = (const __bf16*)(ws + T_FE);
  const int t = threadIdx.x, bo = blockIdx.x;
  const int l = t & 63, wv = t >> 6;
  const int lr = l & 15, lk = l >> 4;

  // ---- stage Cc -> A-frag LDS: row = kx, k = m (Cr) | m+64 (Ci) ----
  const float2* Cp = Cc + (size_t)bo * 2048;
#pragma unroll
  for (int jj = 0; jj < 8; ++jj) {
    int j = t + 256 * jj;
    float2 v = Cp[j];
    int m = j >> 5, kx = j & 31;
    int msK = kx >> 4, lA = ((m >> 3) & 3) * 16 + (kx & 15);
    int e = m & 7, kcR = m >> 5;
    int idxR = ((msK * 4 + kcR) * 64 + lA) * 8 + e;
    int idxI = ((msK * 4 + kcR + 2) * 64 + lA) * 8 + e;
    __bf16 h1 = (__bf16)v.x; CH[idxR] = h1; CL[idxR] = (__bf16)(v.x - (float)h1);
    __bf16 h2 = (__bf16)v.y; CH[idxI] = h2; CL[idxI] = (__bf16)(v.y - (float)h2);
  }
  __syncthreads();

  // ---- D phase (transposed): z1 = Yre^T, z2 = (-Yim)^T ----
  f32x4 z1[2][4], z2[2][4];
#pragma unroll
  for (int m = 0; m < 2; ++m)
#pragma unroll
    for (int n = 0; n < 4; ++n) { z1[m][n] = (f32x4){0.f,0.f,0.f,0.f}; z2[m][n] = (f32x4){0.f,0.f,0.f,0.f}; }
  for (int kc = 0; kc < 4; ++kc) {
    bf16x8 ah[2], al[2];
#pragma unroll
    for (int msK = 0; msK < 2; ++msK) {
      int fo = ((msK * 4 + kc) * 64 + l) * 8;
      ah[msK] = *(const bf16x8*)(CH + fo);
      al[msK] = *(const bf16x8*)(CL + fo);
    }
#pragma unroll
    for (int nsH = 0; nsH < 4; ++nsH) {
      int bo_ = (((wv * 4 + kc) * 4 + nsH) * 64 + l) * 8;
      bf16x8 b1h = *(const bf16x8*)(fd1 + bo_);
      bf16x8 b1l = *(const bf16x8*)(fd1 + 32768 + bo_);
      bf16x8 b2h = *(const bf16x8*)(fd2 + bo_);
      bf16x8 b2l = *(const bf16x8*)(fd2 + 32768 + bo_);
#pragma unroll
      for (int msK = 0; msK < 2; ++msK) {
        z1[msK][nsH] = __builtin_amdgcn_mfma_f32_16x16x32_bf16(ah[msK], b1h, z1[msK][nsH], 0, 0, 0);
        z1[msK][nsH] = __builtin_amdgcn_mfma_f32_16x16x32_bf16(al[msK], b1h, z1[msK][nsH], 0, 0, 0);
        z1[msK][nsH] = __builtin_amdgcn_mfma_f32_16x16x32_bf16(ah[msK], b1l, z1[msK][nsH], 0, 0, 0);
        z2[msK][nsH] = __builtin_amdgcn_mfma_f32_16x16x32_bf16(ah[msK], b2h, z2[msK][nsH], 0, 0, 0);
        z2[msK][nsH] = __builtin_amdgcn_mfma_f32_16x16x32_bf16(al[msK], b2h, z2[msK][nsH], 0, 0, 0);
        z2[msK][nsH] = __builtin_amdgcn_mfma_f32_16x16x32_bf16(ah[msK], b2l, z2[msK][nsH], 0, 0, 0);
      }
    }
  }
  __syncthreads();   // all D-phase CH/CL reads done before region reuse

  // ---- per row-half: wave-local scatter -> E A-frags -> inv-x MFMA -> out ----
  float* ob = out + (size_t)bo * 65536;
  for (int p = 0; p < 2; ++p) {
    // scatter nsH in {2p, 2p+1}: value (msK,nsH,r): kx = msK*16+lk*4+r,
    // h_local = nsH*16+lr; E idx: (((wv*2+q)*2+kcE)*64 + lp)*8 + e
#pragma unroll
    for (int msK = 0; msK < 2; ++msK)
#pragma unroll
      for (int q = 0; q < 2; ++q) {
        int nsH = 2 * p + q;
        int lp = (msK * 2 + (lk >> 1)) * 16 + lr;
        int eb = (lk & 1) * 4;
        int base1 = (((wv * 2 + q) * 2 + 0) * 64 + lp) * 8 + eb;
        int base2 = (((wv * 2 + q) * 2 + 1) * 64 + lp) * 8 + eb;
        B4 p1h, p1l, p2h, p2l;
#pragma unroll
        for (int r = 0; r < 4; ++r) {
          float v1 = z1[msK][nsH][r];
          __bf16 h1 = (__bf16)v1; p1h.b[r] = h1; p1l.b[r] = (__bf16)(v1 - (float)h1);
          float v2 = z2[msK][nsH][r];
          __bf16 h2 = (__bf16)v2; p2h.b[r] = h2; p2l.b[r] = (__bf16)(v2 - (float)h2);
        }
        *(uint2*)&EH[base1] = p1h.u; *(uint2*)&EL[base1] = p1l.u;
        *(uint2*)&EH[base2] = p2h.u; *(uint2*)&EL[base2] = p2l.u;
      }
    // wave-local handoff: no __syncthreads needed (same-wave LDS ordering)
    bf16x8 ah[2][2], al[2][2];
#pragma unroll
    for (int q = 0; q < 2; ++q)
#pragma unroll
      for (int kc = 0; kc < 2; ++kc) {
        int fo = (((wv * 2 + q) * 2 + kc) * 64 + l) * 8;
        ah[q][kc] = *(const bf16x8*)(EH + fo);
        al[q][kc] = *(const bf16x8*)(EL + fo);
      }
    for (int cb = 0; cb < 4; ++cb) {
      f32x4 eacc[2][4];
#pragma unroll
      for (int m = 0; m < 2; ++m)
#pragma unroll
        for (int n = 0; n < 4; ++n) eacc[m][n] = (f32x4){0.f, 0.f, 0.f, 0.f};
#pragma unroll
      for (int kc = 0; kc < 2; ++kc) {
        bf16x8 bh[4], bl[4];
#pragma unroll
        for (int ns = 0; ns < 4; ++ns) {
          int fo = ((kc * 16 + cb * 4 + ns) * 64 + l) * 8;
          bh[ns] = *(const bf16x8*)(frE + fo);
          bl[ns] = *(const bf16x8*)(frE + 16384 + fo);
        }
#pragma unroll
        for (int q = 0; q < 2; ++q)
#pragma unroll
          for (int ns = 0; ns < 4; ++ns) {
            eacc[q][ns] = __builtin_amdgcn_mfma_f32_16x16x32_bf16(ah[q][kc], bh[ns], eacc[q][ns], 0, 0, 0);
            eacc[q][ns] = __builtin_amdgcn_mfma_f32_16x16x32_bf16(al[q][kc], bh[ns], eacc[q][ns], 0, 0, 0);
            eacc[q][ns] = __builtin_amdgcn_mfma_f32_16x16x32_bf16(ah[q][kc], bl[ns], eacc[q][ns], 0, 0, 0);
          }
      }
#pragma unroll
      for (int q = 0; q < 2; ++q)
#pragma unroll
        for (int ns = 0; ns < 4; ++ns) {
          int col = cb * 64 + ns * 16 + lr;
          int row0 = wv * 64 + (2 * p + q) * 16 + lk * 4;
#pragma unroll
          for (int r = 0; r < 4; ++r)
            ob[(size_t)(row0 + r) * 256 + col] = eacc[q][ns][r];
        }
    }
  }
}

extern "C" void kernel_launch(void* const* d_in, const int* in_sizes, int n_in,
                              void* d_out, int out_size, void* d_ws, size_t ws_size,
                              hipStream_t stream) {
  (void)in_sizes; (void)n_in; (void)out_size; (void)ws_size;
  const float* x   = (const float*)d_in[0];
  const float* wpr = (const float*)d_in[1];
  const float* wpi = (const float*)d_in[2];
  const float* wnr = (const float*)d_in[3];
  const float* wni = (const float*)d_in[4];
  float* out = (float*)d_out;
  float* ws  = (float*)d_ws;

  float2* X2 = (float2*)(ws + T_X2);   // [1024][2048] float2
  float2* Cc = (float2*)(ws + T_CC);   // [1024][2048] float2

  k_prep<<<512, 256, 0, stream>>>(ws);
  k_AB<<<1024, 256, 0, stream>>>(x, ws, X2);
  k_C<<<1024, 256, 0, stream>>>(X2, wpr, wpi, wnr, wni, Cc);
  k_DE<<<1024, 256, 0, stream>>>(Cc, ws, out);
}

// Round 11
// 214.193 us; speedup vs baseline: 1.7418x; 1.2527x over previous
//
#include <hip/hip_runtime.h>
#include <math.h>

#define PI_F 3.14159265358979323846f

// x:[16][64][256][256] f32, weights ×4:[64][64][32][32] f32, out:[16][64][256][256] f32
// modes: ky m=0..63 -> ky = m (m<32) else m+192 ; kx = 0..31
//
// Fully-MFMA pipeline (X2/Cc + frag tables in d_ws):
//   AB: per bi: ONE-SHOT x-DFT MFMA (4 M-subtiles/wave, x reg-prefetched 1 kc
//       ahead) -> 64KB LDS B-frags (packed b64 scatter) -> y-DFT MFMA -> X2
//   C : coalesced-mode channel mix (lanes span modes; W read once, coalesced)
//   DE: Cc -> A-frags (16KB); TRANSPOSED inv-y MFMA -> barrier -> 32KB LDS
//       region reused: per row-half, wave-local packed scatter -> inv-x -> out
//
// LESSONS: (R9) __launch_bounds__ min-waves >2 spills MFMA accumulators ->
// 225MB scratch writes, 4x slower. (R10) two-half AB halves ILP and doubles
// table traffic: -60us. Keep one-shot AB + (256,2) everywhere.
//
// Frag conventions (R6-R8 validated):
//   A-frag: row = lane&15, k = (lane>>4)*8 + e
//   B-frag: col = lane&15, k = (lane>>4)*8 + e
//   C/D   : col = lane&15, row = (lane>>4)*4 + reg

static constexpr int T_FA  = 0;         // x-DFT B-frag table  hi|lo (32768 bf16)
static constexpr int T_FE  = 16384;     // inv-x  B-frag table hi|lo (32768 bf16)
static constexpr int T_FBC = 32768;     // y-DFT Cy A-frag     hi|lo (32768 bf16)
static constexpr int T_FBS = 49152;     // y-DFT Sy A-frag     hi|lo (32768 bf16)
static constexpr int T_FD1 = 65536;     // inv-y T1 B-frag     hi|lo (65536 bf16)
static constexpr int T_FD2 = 98304;     // inv-y T2 B-frag     hi|lo (65536 bf16)
static constexpr int T_X2  = 131072;                 // [1024][2048] float2
static constexpr int T_CC  = 131072 + 4194304;       // [1024][2048] float2

typedef __attribute__((ext_vector_type(8))) __bf16 bf16x8;
typedef __attribute__((ext_vector_type(4))) float f32x4;

union B4 { __bf16 b[4]; uint2 u; };

// ---------------- fragment tables ----------------
__global__ __launch_bounds__(256) void k_prep(float* __restrict__ ws) {
  int idx = blockIdx.x * 256 + threadIdx.x;
  const float C = 2.0f * PI_F / 256.0f;
  if (idx < 16384) {
    // FA: B[n=col][k=w]; frag q = kc*4+ns (kc<8)
    int j = idx;
    int e = j & 7, l = (j >> 3) & 63, q = j >> 9;
    int ns = q & 3, kc = q >> 2;
    int w = kc * 32 + ((l >> 4) & 3) * 8 + e;
    int col = ns * 16 + (l & 15);
    int kxi = col & 31;
    float ang = C * (float)((kxi * w) & 255);
    float v = (col < 32) ? cosf(ang) : -sinf(ang);
    __bf16 hv = (__bf16)v;
    __bf16 lv = (__bf16)(v - (float)hv);
    __bf16* fr = (__bf16*)(ws + T_FA);
    fr[j] = hv; fr[16384 + j] = lv;
  } else if (idx < 32768) {
    // FE: B[n=w][k=c]; frag q = kc*16+wblk (kc<2)
    int j = idx - 16384;
    int e = j & 7, l = (j >> 3) & 63, q = j >> 9;
    int wb = q & 15, kc = q >> 4;
    int c = kc * 32 + ((l >> 4) & 3) * 8 + e;
    int w = wb * 16 + (l & 15);
    int kxi = (c < 32) ? c : (c - 32);
    float ang = C * (float)((kxi * w) & 255);
    float v = (c < 32) ? cosf(ang) : sinf(ang);
    __bf16 hv = (__bf16)v;
    __bf16 lv = (__bf16)(v - (float)hv);
    __bf16* fr = (__bf16*)(ws + T_FE);
    fr[j] = hv; fr[16384 + j] = lv;
  } else if (idx < 65536) {
    // FBC/FBS: A[row=m][k=h]; frag q = kc*4+ms4 (kc<8)
    int base = (idx < 49152) ? 32768 : 49152;
    int j = idx - base;
    int e = j & 7, l = (j >> 3) & 63, q = j >> 9;
    int ms4 = q & 3, kc = q >> 2;
    int m = ms4 * 16 + (l & 15);
    int h = kc * 32 + ((l >> 4) & 3) * 8 + e;
    int ky = (m < 32) ? m : (m + 192);
    float ang = C * (float)((ky * h) & 255);
    float v = (idx < 49152) ? cosf(ang) : sinf(ang);
    __bf16 hv = (__bf16)v;
    __bf16 lv = (__bf16)(v - (float)hv);
    __bf16* fr = (__bf16*)(ws + base);
    fr[j] = hv; fr[16384 + j] = lv;
  } else if (idx < 131072) {
    // FD1/FD2: B[k = m-stack 128][col = h]; frag f = (wv*4+kc)*4+nsH
    int base = (idx < 98304) ? T_FD1 : T_FD2;
    int j = idx - base;
    int e = j & 7, l = (j >> 3) & 63, f = j >> 9;     // f 0..63
    int nsH = f & 3, kc = (f >> 2) & 3, wv = f >> 4;
    int h = wv * 64 + nsH * 16 + (l & 15);
    int k = kc * 32 + ((l >> 4) & 3) * 8 + e;
    int m = (k < 64) ? k : (k - 64);
    int ky = (m < 32) ? m : (m + 192);
    float ang = C * (float)((ky * h) & 255);
    float cv = cosf(ang), sv = sinf(ang);
    float v;
    if (idx < 98304) v = (k < 64) ? cv : -sv;    // T1:  cy | -sy  -> Yre
    else             v = (k < 64) ? -sv : -cv;   // T2: -sy | -cy  -> -Yim
    __bf16 hv = (__bf16)v;
    __bf16 lv = (__bf16)(v - (float)hv);
    __bf16* fr = (__bf16*)(ws + base);
    fr[j] = hv; fr[32768 + j] = lv;
  }
}

// split two float4 registers (8 floats) into hi/lo bf16x8 fragments
__device__ __forceinline__ void cvt_split8r(float4 a, float4 b,
                                            bf16x8& h, bf16x8& l) {
#define CVS(e, vv) { __bf16 hh = (__bf16)(vv); h[e] = hh; l[e] = (__bf16)((vv) - (float)hh); }
  CVS(0, a.x) CVS(1, a.y) CVS(2, a.z) CVS(3, a.w)
  CVS(4, b.x) CVS(5, b.y) CVS(6, b.z) CVS(7, b.w)
#undef CVS
}

// ---------------- AB: x-DFT + y-DFT, all MFMA, one-shot (64KB LDS) ----------------
__global__ __launch_bounds__(256, 2) void k_AB(const float* __restrict__ x,
                                               const float* __restrict__ ws,
                                               float2* __restrict__ X2) {
  __shared__ __bf16 AsH[16384];
  __shared__ __bf16 AsL[16384];
  const __bf16* frA = (const __bf16*)(ws + T_FA);
  const __bf16* fbc = (const __bf16*)(ws + T_FBC);
  const __bf16* fbs = (const __bf16*)(ws + T_FBS);
  const int t = threadIdx.x, bi = blockIdx.x;
  const int l = t & 63, wv = t >> 6;
  const int lr = l & 15, lk = l >> 4;

  // ---- A phase: wave wv owns rows wv*64..+63 (4 M-subtiles) ----
  f32x4 acc[4][4];
#pragma unroll
  for (int m = 0; m < 4; ++m)
#pragma unroll
    for (int n = 0; n < 4; ++n) acc[m][n] = (f32x4){0.f, 0.f, 0.f, 0.f};
  const float* xb = x + (size_t)bi * 65536 + (size_t)(wv * 64 + lr) * 256 + lk * 8;
  // register prefetch: x for kc=0
  float4 xA[4], xB[4];
#pragma unroll
  for (int ms = 0; ms < 4; ++ms) {
    const float* p = xb + ms * 16 * 256;
    xA[ms] = *(const float4*)p;
    xB[ms] = *(const float4*)(p + 4);
  }
  for (int kc = 0; kc < 8; ++kc) {
    bf16x8 ah[4], al[4];
#pragma unroll
    for (int ms = 0; ms < 4; ++ms)
      cvt_split8r(xA[ms], xB[ms], ah[ms], al[ms]);
    if (kc < 7) {   // issue next kc's x loads; latency hides under MFMA burst
#pragma unroll
      for (int ms = 0; ms < 4; ++ms) {
        const float* p = xb + ms * 16 * 256 + (kc + 1) * 32;
        xA[ms] = *(const float4*)p;
        xB[ms] = *(const float4*)(p + 4);
      }
    }
    bf16x8 bh[4], bl[4];
#pragma unroll
    for (int ns = 0; ns < 4; ++ns) {
      int fo = ((kc * 4 + ns) * 64 + l) * 8;
      bh[ns] = *(const bf16x8*)(frA + fo);
      bl[ns] = *(const bf16x8*)(frA + 16384 + fo);
    }
#pragma unroll
    for (int ms = 0; ms < 4; ++ms)
#pragma unroll
      for (int ns = 0; ns < 4; ++ns) {
        acc[ms][ns] = __builtin_amdgcn_mfma_f32_16x16x32_bf16(ah[ms], bh[ns], acc[ms][ns], 0, 0, 0);
        acc[ms][ns] = __builtin_amdgcn_mfma_f32_16x16x32_bf16(al[ms], bh[ns], acc[ms][ns], 0, 0, 0);
        acc[ms][ns] = __builtin_amdgcn_mfma_f32_16x16x32_bf16(ah[ms], bl[ns], acc[ms][ns], 0, 0, 0);
      }
  }
  // ---- packed scatter -> LDS B-frags ----
#pragma unroll
  for (int ms = 0; ms < 4; ++ms)
#pragma unroll
    for (int ns = 0; ns < 4; ++ns) {
      int kcB = wv * 2 + (ms >> 1);
      int quad = (ms & 1) * 2 + (lk >> 1);
      int base = ((kcB * 4 + ns) * 64 + quad * 16 + lr) * 8 + (lk & 1) * 4;
      B4 ph, pl;
#pragma unroll
      for (int r = 0; r < 4; ++r) {
        float v = acc[ms][ns][r];
        __bf16 hv = (__bf16)v;
        ph.b[r] = hv; pl.b[r] = (__bf16)(v - (float)hv);
      }
      *(uint2*)&AsH[base] = ph.u;
      *(uint2*)&AsL[base] = pl.u;
    }
  __syncthreads();

  // ---- B phase ----
  f32x4 cyA[4], syA[4];
#pragma unroll
  for (int n = 0; n < 4; ++n) { cyA[n] = (f32x4){0.f,0.f,0.f,0.f}; syA[n] = (f32x4){0.f,0.f,0.f,0.f}; }
  for (int kc = 0; kc < 8; ++kc) {
    bf16x8 Bh[4], Bl[4];
#pragma unroll
    for (int ns = 0; ns < 4; ++ns) {
      int fo = ((kc * 4 + ns) * 64 + l) * 8;
      Bh[ns] = *(const bf16x8*)(AsH + fo);
      Bl[ns] = *(const bf16x8*)(AsL + fo);
    }
    int ao = ((kc * 4 + wv) * 64 + l) * 8;
    bf16x8 cyh = *(const bf16x8*)(fbc + ao);
    bf16x8 cyl = *(const bf16x8*)(fbc + 16384 + ao);
    bf16x8 syh = *(const bf16x8*)(fbs + ao);
    bf16x8 syl = *(const bf16x8*)(fbs + 16384 + ao);
#pragma unroll
    for (int ns = 0; ns < 4; ++ns) {
      cyA[ns] = __builtin_amdgcn_mfma_f32_16x16x32_bf16(cyh, Bh[ns], cyA[ns], 0, 0, 0);
      cyA[ns] = __builtin_amdgcn_mfma_f32_16x16x32_bf16(cyl, Bh[ns], cyA[ns], 0, 0, 0);
      cyA[ns] = __builtin_amdgcn_mfma_f32_16x16x32_bf16(cyh, Bl[ns], cyA[ns], 0, 0, 0);
      syA[ns] = __builtin_amdgcn_mfma_f32_16x16x32_bf16(syh, Bh[ns], syA[ns], 0, 0, 0);
      syA[ns] = __builtin_amdgcn_mfma_f32_16x16x32_bf16(syl, Bh[ns], syA[ns], 0, 0, 0);
      syA[ns] = __builtin_amdgcn_mfma_f32_16x16x32_bf16(syh, Bl[ns], syA[ns], 0, 0, 0);
    }
  }
  // ---- combine halves and store X2 ----
#pragma unroll
  for (int ns = 0; ns < 2; ++ns)
#pragma unroll
    for (int r = 0; r < 4; ++r) {
      int m = wv * 16 + lk * 4 + r;
      int kx = ns * 16 + lr;
      float re = cyA[ns][r] + syA[ns + 2][r];
      float im = cyA[ns + 2][r] - syA[ns][r];
      X2[(size_t)bi * 2048 + m * 32 + kx] = make_float2(re, im);
    }
}

// ---------------- C: channel mix, coalesced-mode ----------------
// grid 1024: mc = bid&63 (32-mode chunk), ot = bid>>6 (4-o tile).
// bid%8 = mc%8 -> all 16 ot-blocks of a mode-chunk share one XCD's L2.
__global__ __launch_bounds__(256, 4) void k_C(const float2* __restrict__ X2,
                                              const float* __restrict__ wpr,
                                              const float* __restrict__ wpi,
                                              const float* __restrict__ wnr,
                                              const float* __restrict__ wni,
                                              float2* __restrict__ Cc) {
  __shared__ float2 Xs[2][16][32];     // [buf][b][md]
  __shared__ float2 Ws[2][4][4][32];   // [buf][iS][og][md]
  const int t = threadIdx.x;
  const int mc = blockIdx.x & 63, ot = blockIdx.x >> 6;
  const int mode0 = mc * 32;
  const float *wr, *wi; int wm0;
  if (mode0 < 1024) { wr = wpr; wi = wpi; wm0 = mode0; }
  else              { wr = wnr; wi = wni; wm0 = mode0 - 1024; }
  const int md = t & 31, og2 = (t >> 5) & 1, bq = t >> 6;
  const int bS = t >> 4, c2 = (t & 15) * 2;
  const int e0 = t * 2;
  const int wiS = e0 >> 7, wog = (e0 >> 5) & 3, wmd = e0 & 31;

  float ar[4][2], ai[4][2];
#pragma unroll
  for (int b = 0; b < 4; ++b) { ar[b][0]=0.f; ar[b][1]=0.f; ai[b][0]=0.f; ai[b][1]=0.f; }

  *(float4*)&Xs[0][bS][c2] =
      *(const float4*)&X2[((size_t)(bS * 64 + 0)) * 2048 + mode0 + c2];
  {
    size_t wa = ((size_t)(wiS * 64) + ot * 4 + wog) * 1024 + wm0 + wmd;
    float2 r2 = *(const float2*)&wr[wa];
    float2 i2 = *(const float2*)&wi[wa];
    Ws[0][wiS][wog][wmd]     = make_float2(r2.x, i2.x);
    Ws[0][wiS][wog][wmd + 1] = make_float2(r2.y, i2.y);
  }
  __syncthreads();

  for (int i = 0; i < 64; ++i) {
    const int cur = i & 1, wcur = (i >> 2) & 1;
    if (i < 63)
      *(float4*)&Xs[cur ^ 1][bS][c2] =
          *(const float4*)&X2[((size_t)(bS * 64 + i + 1)) * 2048 + mode0 + c2];
    if ((i & 3) == 0 && i < 60) {
      size_t wa = ((size_t)((i + 4 + wiS) * 64) + ot * 4 + wog) * 1024 + wm0 + wmd;
      float2 r2 = *(const float2*)&wr[wa];
      float2 i2 = *(const float2*)&wi[wa];
      Ws[wcur ^ 1][wiS][wog][wmd]     = make_float2(r2.x, i2.x);
      Ws[wcur ^ 1][wiS][wog][wmd + 1] = make_float2(r2.y, i2.y);
    }
    float2 w0 = Ws[wcur][i & 3][og2 * 2 + 0][md];
    float2 w1 = Ws[wcur][i & 3][og2 * 2 + 1][md];
#pragma unroll
    for (int b = 0; b < 4; ++b) {
      float2 xv = Xs[cur][bq * 4 + b][md];
      ar[b][0] = fmaf(xv.x, w0.x, fmaf(-xv.y, w0.y, ar[b][0]));
      ai[b][0] = fmaf(xv.x, w0.y, fmaf( xv.y, w0.x, ai[b][0]));
      ar[b][1] = fmaf(xv.x, w1.x, fmaf(-xv.y, w1.y, ar[b][1]));
      ai[b][1] = fmaf(xv.x, w1.y, fmaf( xv.y, w1.x, ai[b][1]));
    }
    __syncthreads();
  }

  const float scale = ((md == 0) ? 1.f : 2.f) * (1.f / 65536.f);
#pragma unroll
  for (int b = 0; b < 4; ++b)
#pragma unroll
    for (int o2 = 0; o2 < 2; ++o2)
      Cc[((size_t)((bq * 4 + b) * 64 + ot * 4 + og2 * 2 + o2)) * 2048 + mode0 + md] =
          make_float2(ar[b][o2] * scale, ai[b][o2] * scale);
}

// ---------------- DE: transposed inv-y + inv-x + Re(), 32KB aliased LDS ----------------
__global__ __launch_bounds__(256, 2) void k_DE(const float2* __restrict__ Cc,
                                               const float* __restrict__ ws,
                                               float* __restrict__ out) {
  __shared__ __bf16 smem[16384];            // 32KB, time-shared
  __bf16* CH = smem;                        // phase 1: Cstack^T A-frags hi (8KB)
  __bf16* CL = smem + 4096;                 //          lo (8KB)
  __bf16* EH = smem;                        // phase 2: Y E-A-frags (row-half) hi (16KB)
  __bf16* EL = smem + 8192;                 //          lo (16KB)
  const __bf16* fd1 = (const __bf16*)(ws + T_FD1);
  const __bf16* fd2 = (const __bf16*)(ws + T_FD2);
  const __bf16* frE = (const __bf16*)(ws + T_FE);
  const int t = threadIdx.x, bo = blockIdx.x;
  const int l = t & 63, wv = t >> 6;
  const int lr = l & 15, lk = l >> 4;

  // ---- stage Cc -> A-frag LDS: row = kx, k = m (Cr) | m+64 (Ci) ----
  const float2* Cp = Cc + (size_t)bo * 2048;
#pragma unroll
  for (int jj = 0; jj < 8; ++jj) {
    int j = t + 256 * jj;
    float2 v = Cp[j];
    int m = j >> 5, kx = j & 31;
    int msK = kx >> 4, lA = ((m >> 3) & 3) * 16 + (kx & 15);
    int e = m & 7, kcR = m >> 5;
    int idxR = ((msK * 4 + kcR) * 64 + lA) * 8 + e;
    int idxI = ((msK * 4 + kcR + 2) * 64 + lA) * 8 + e;
    __bf16 h1 = (__bf16)v.x; CH[idxR] = h1; CL[idxR] = (__bf16)(v.x - (float)h1);
    __bf16 h2 = (__bf16)v.y; CH[idxI] = h2; CL[idxI] = (__bf16)(v.y - (float)h2);
  }
  __syncthreads();

  // ---- D phase (transposed): z1 = Yre^T, z2 = (-Yim)^T ----
  f32x4 z1[2][4], z2[2][4];
#pragma unroll
  for (int m = 0; m < 2; ++m)
#pragma unroll
    for (int n = 0; n < 4; ++n) { z1[m][n] = (f32x4){0.f,0.f,0.f,0.f}; z2[m][n] = (f32x4){0.f,0.f,0.f,0.f}; }
  for (int kc = 0; kc < 4; ++kc) {
    bf16x8 ah[2], al[2];
#pragma unroll
    for (int msK = 0; msK < 2; ++msK) {
      int fo = ((msK * 4 + kc) * 64 + l) * 8;
      ah[msK] = *(const bf16x8*)(CH + fo);
      al[msK] = *(const bf16x8*)(CL + fo);
    }
#pragma unroll
    for (int nsH = 0; nsH < 4; ++nsH) {
      int bo_ = (((wv * 4 + kc) * 4 + nsH) * 64 + l) * 8;
      bf16x8 b1h = *(const bf16x8*)(fd1 + bo_);
      bf16x8 b1l = *(const bf16x8*)(fd1 + 32768 + bo_);
      bf16x8 b2h = *(const bf16x8*)(fd2 + bo_);
      bf16x8 b2l = *(const bf16x8*)(fd2 + 32768 + bo_);
#pragma unroll
      for (int msK = 0; msK < 2; ++msK) {
        z1[msK][nsH] = __builtin_amdgcn_mfma_f32_16x16x32_bf16(ah[msK], b1h, z1[msK][nsH], 0, 0, 0);
        z1[msK][nsH] = __builtin_amdgcn_mfma_f32_16x16x32_bf16(al[msK], b1h, z1[msK][nsH], 0, 0, 0);
        z1[msK][nsH] = __builtin_amdgcn_mfma_f32_16x16x32_bf16(ah[msK], b1l, z1[msK][nsH], 0, 0, 0);
        z2[msK][nsH] = __builtin_amdgcn_mfma_f32_16x16x32_bf16(ah[msK], b2h, z2[msK][nsH], 0, 0, 0);
        z2[msK][nsH] = __builtin_amdgcn_mfma_f32_16x16x32_bf16(al[msK], b2h, z2[msK][nsH], 0, 0, 0);
        z2[msK][nsH] = __builtin_amdgcn_mfma_f32_16x16x32_bf16(ah[msK], b2l, z2[msK][nsH], 0, 0, 0);
      }
    }
  }
  __syncthreads();   // all D-phase CH/CL reads done before region reuse

  // ---- per row-half: wave-local scatter -> E A-frags -> inv-x MFMA -> out ----
  float* ob = out + (size_t)bo * 65536;
  for (int p = 0; p < 2; ++p) {
#pragma unroll
    for (int msK = 0; msK < 2; ++msK)
#pragma unroll
      for (int q = 0; q < 2; ++q) {
        int nsH = 2 * p + q;
        int lp = (msK * 2 + (lk >> 1)) * 16 + lr;
        int eb = (lk & 1) * 4;
        int base1 = (((wv * 2 + q) * 2 + 0) * 64 + lp) * 8 + eb;
        int base2 = (((wv * 2 + q) * 2 + 1) * 64 + lp) * 8 + eb;
        B4 p1h, p1l, p2h, p2l;
#pragma unroll
        for (int r = 0; r < 4; ++r) {
          float v1 = z1[msK][nsH][r];
          __bf16 h1 = (__bf16)v1; p1h.b[r] = h1; p1l.b[r] = (__bf16)(v1 - (float)h1);
          float v2 = z2[msK][nsH][r];
          __bf16 h2 = (__bf16)v2; p2h.b[r] = h2; p2l.b[r] = (__bf16)(v2 - (float)h2);
        }
        *(uint2*)&EH[base1] = p1h.u; *(uint2*)&EL[base1] = p1l.u;
        *(uint2*)&EH[base2] = p2h.u; *(uint2*)&EL[base2] = p2l.u;
      }
    // wave-local handoff: no __syncthreads needed (same-wave LDS ordering)
    bf16x8 ah[2][2], al[2][2];
#pragma unroll
    for (int q = 0; q < 2; ++q)
#pragma unroll
      for (int kc = 0; kc < 2; ++kc) {
        int fo = (((wv * 2 + q) * 2 + kc) * 64 + l) * 8;
        ah[q][kc] = *(const bf16x8*)(EH + fo);
        al[q][kc] = *(const bf16x8*)(EL + fo);
      }
    for (int cb = 0; cb < 4; ++cb) {
      f32x4 eacc[2][4];
#pragma unroll
      for (int m = 0; m < 2; ++m)
#pragma unroll
        for (int n = 0; n < 4; ++n) eacc[m][n] = (f32x4){0.f, 0.f, 0.f, 0.f};
#pragma unroll
      for (int kc = 0; kc < 2; ++kc) {
        bf16x8 bh[4], bl[4];
#pragma unroll
        for (int ns = 0; ns < 4; ++ns) {
          int fo = ((kc * 16 + cb * 4 + ns) * 64 + l) * 8;
          bh[ns] = *(const bf16x8*)(frE + fo);
          bl[ns] = *(const bf16x8*)(frE + 16384 + fo);
        }
#pragma unroll
        for (int q = 0; q < 2; ++q)
#pragma unroll
          for (int ns = 0; ns < 4; ++ns) {
            eacc[q][ns] = __builtin_amdgcn_mfma_f32_16x16x32_bf16(ah[q][kc], bh[ns], eacc[q][ns], 0, 0, 0);
            eacc[q][ns] = __builtin_amdgcn_mfma_f32_16x16x32_bf16(al[q][kc], bh[ns], eacc[q][ns], 0, 0, 0);
            eacc[q][ns] = __builtin_amdgcn_mfma_f32_16x16x32_bf16(ah[q][kc], bl[ns], eacc[q][ns], 0, 0, 0);
          }
      }
#pragma unroll
      for (int q = 0; q < 2; ++q)
#pragma unroll
        for (int ns = 0; ns < 4; ++ns) {
          int col = cb * 64 + ns * 16 + lr;
          int row0 = wv * 64 + (2 * p + q) * 16 + lk * 4;
#pragma unroll
          for (int r = 0; r < 4; ++r)
            ob[(size_t)(row0 + r) * 256 + col] = eacc[q][ns][r];
        }
    }
  }
}

extern "C" void kernel_launch(void* const* d_in, const int* in_sizes, int n_in,
                              void* d_out, int out_size, void* d_ws, size_t ws_size,
                              hipStream_t stream) {
  (void)in_sizes; (void)n_in; (void)out_size; (void)ws_size;
  const float* x   = (const float*)d_in[0];
  const float* wpr = (const float*)d_in[1];
  const float* wpi = (const float*)d_in[2];
  const float* wnr = (const float*)d_in[3];
  const float* wni = (const float*)d_in[4];
  float* out = (float*)d_out;
  float* ws  = (float*)d_ws;

  float2* X2 = (float2*)(ws + T_X2);   // [1024][2048] float2
  float2* Cc = (float2*)(ws + T_CC);   // [1024][2048] float2

  k_prep<<<512, 256, 0, stream>>>(ws);
  k_AB<<<1024, 256, 0, stream>>>(x, ws, X2);
  k_C<<<1024, 256, 0, stream>>>(X2, wpr, wpi, wnr, wni, Cc);
  k_DE<<<1024, 256, 0, stream>>>(Cc, ws, out);
}